// Round 8
// baseline (195.948 us; speedup 1.0000x reference)
//
#include <hip/hip_runtime.h>

// RetrosynthesisAttention, B=16, N=M=D=U=256, fp32 — split-phase build:
//   proj_kernel  : LDS-FREE projection GEMMs (W via wave-uniform SGPR loads,
//                  X via imm-offset float4 streams) + exp2 epilogue
//   logit_kernel : partial logits, u-split x2 (blockIdx.z), 8-way rcp combine
//   smctx_kernel : partial-sum + softmax + d-quad float4 context
//
// Math: tanh(x) = 1 - 2/(exp2(Kx)+1); constants cancel in softmax.
// z_u = rcpc(v_u)*2^-16 + E'_u*(D_u*rcpc(v_u)), E' = exp2(K*ep-16), D*rcpc(v)
// precomputed; sum 1/z over 8 u's with ONE v_rcp (tree combine).

constexpr float KSC   = 2.8853900817779268f;   // 2*log2(e)
constexpr float LOG2E = 1.4426950408889634f;
constexpr float S16   = 1.52587890625e-05f;    // 2^-16
constexpr float LSC   = -3.0517578125e-05f;    // -2^-15

struct F4 { float v[4]; };
__device__ __forceinline__ F4 ld4(const float* p) {
    float4 t = *(const float4*)p;
    F4 r; r.v[0] = t.x; r.v[1] = t.y; r.v[2] = t.z; r.v[3] = t.w; return r;
}
__device__ __forceinline__ float rcp_clamp(float v) {
    float r = __builtin_amdgcn_rcpf(v);
    return fminf(fmaxf(r, -1e4f), 1e4f);   // identical in all kernels
}

// ---------------- Kernel 1: LDS-free projection GEMMs + exp2 epilogue.
// Block = 128 rows x 16 u, 256 thr: lane (0..63) owns row-pair, wave (0..3)
// owns a u-quad. W addresses are wave-uniform (readfirstlane -> SGPR base,
// scalar/broadcast loads, L1-resident); X rows are per-lane float4 streams
// with immediate offsets. No LDS, no barriers. Grid (16,64) = 1024 blocks.
__global__ __launch_bounds__(256) void proj_kernel(
    const float* __restrict__ enc, const float* __restrict__ dec,
    const float* __restrict__ W1,  const float* __restrict__ b1,
    const float* __restrict__ W2,  const float* __restrict__ b2,
    const float* __restrict__ vw,
    float* __restrict__ encQ, float* __restrict__ decE)
{
    const int tid  = threadIdx.x;
    const int lane = tid & 63;
    const int w    = __builtin_amdgcn_readfirstlane(tid >> 6);  // 0..3, SGPR
    const int ublk = blockIdx.x;        // 0..15
    const int rblk = blockIdx.y;        // 0..63
    const bool is_enc = rblk < 32;
    const float* X    = is_enc ? enc : dec;
    const float* W    = is_enc ? W1  : W2;
    const float* bias = is_enc ? b1  : b2;
    const int rb = (is_enc ? rblk : rblk - 32) * 128;
    const int r0 = rb + (lane << 1);    // this thread's row pair
    const int u0 = (ublk << 4) + (w << 2);

    const float* x0p = X + r0 * 256;
    const float* x1p = x0p + 256;
    const float* wp  = W + u0;          // SGPR base (u0 wave-uniform)

    float acc[2][4] = {};
    #pragma unroll 8
    for (int kq = 0; kq < 64; ++kq) {
        const F4 xa = ld4(x0p + (kq << 2));
        const F4 xb = ld4(x1p + (kq << 2));
        const F4 w0 = ld4(wp + ((kq << 2) + 0) * 256);
        const F4 w1 = ld4(wp + ((kq << 2) + 1) * 256);
        const F4 w2 = ld4(wp + ((kq << 2) + 2) * 256);
        const F4 w3 = ld4(wp + ((kq << 2) + 3) * 256);
        #pragma unroll
        for (int i = 0; i < 4; ++i) {
            acc[0][i] = fmaf(xa.v[0], w0.v[i], acc[0][i]);
            acc[1][i] = fmaf(xb.v[0], w0.v[i], acc[1][i]);
            acc[0][i] = fmaf(xa.v[1], w1.v[i], acc[0][i]);
            acc[1][i] = fmaf(xb.v[1], w1.v[i], acc[1][i]);
            acc[0][i] = fmaf(xa.v[2], w2.v[i], acc[0][i]);
            acc[1][i] = fmaf(xb.v[2], w2.v[i], acc[1][i]);
            acc[0][i] = fmaf(xa.v[3], w3.v[i], acc[0][i]);
            acc[1][i] = fmaf(xb.v[3], w3.v[i], acc[1][i]);
        }
    }

    const F4 bb = ld4(&bias[u0]);
    if (is_enc) {
        const int uq = u0 >> 2;
        #pragma unroll
        for (int i = 0; i < 2; ++i) {
            const int r = r0 + i, b = r >> 8, m = r & 255;
            float4 o;
            o.x = __builtin_amdgcn_exp2f(fmaf(KSC, acc[i][0] + bb.v[0], -16.f));
            o.y = __builtin_amdgcn_exp2f(fmaf(KSC, acc[i][1] + bb.v[1], -16.f));
            o.z = __builtin_amdgcn_exp2f(fmaf(KSC, acc[i][2] + bb.v[2], -16.f));
            o.w = __builtin_amdgcn_exp2f(fmaf(KSC, acc[i][3] + bb.v[3], -16.f));
            *(float4*)&encQ[b * 65536 + uq * 1024 + m * 4] = o;
        }
    } else {
        const F4 vv = ld4(&vw[u0]);
        float rv[4];
        #pragma unroll
        for (int j = 0; j < 4; ++j) rv[j] = rcp_clamp(vv.v[j]);
        #pragma unroll
        for (int i = 0; i < 2; ++i) {
            float4 o;
            o.x = __builtin_amdgcn_exp2f(KSC * (acc[i][0] + bb.v[0])) * rv[0];
            o.y = __builtin_amdgcn_exp2f(KSC * (acc[i][1] + bb.v[1])) * rv[1];
            o.z = __builtin_amdgcn_exp2f(KSC * (acc[i][2] + bb.v[2])) * rv[2];
            o.w = __builtin_amdgcn_exp2f(KSC * (acc[i][3] + bb.v[3])) * rv[3];
            *(float4*)&decE[(r0 + i) * 256 + u0] = o;
        }
    }
}

// ---------------- Kernel 2: partial logits. u-split x2 via blockIdx.z.
// 512 thr (8 waves), n-tile 8 (half h owns 4 chains), m = tid&255.
// Grid (32,16,2) = 1024 blocks -> 4 blk/CU, 32 waves/CU theoretical.
__global__ __launch_bounds__(512) void logit_kernel(
    const float* __restrict__ encQ,  // [b][u/4][m][4] = exp2(K*ep-16)
    const float* __restrict__ decE,  // [n_flat][u]    = exp2(K*dp)*rcpc(v)
    const float* __restrict__ vw,    // [U]
    float* __restrict__ part)        // [2][B][N][M] partial logits
{
    __shared__ float dsD[8][128];
    __shared__ float vcs[128];

    const int tid  = threadIdx.x;    // 0..511
    const int b    = blockIdx.y;
    const int n0   = blockIdx.x << 3;
    const int half = blockIdx.z;     // u in [half*128, half*128+128)
    const int h    = tid >> 8;
    const int m    = tid & 255;
    const int t0   = h << 2;

    {   // stage half of decE rows n0..n0+7 and vcs for this u-half
        #pragma unroll
        for (int rep = 0; rep < 2; ++rep) {
            const int idx = tid + (rep << 9);      // 0..1023
            const int i = idx >> 7, u = idx & 127;
            dsD[i][u] = decE[(b * 256 + n0 + i) * 256 + half * 128 + u];
        }
        if (tid < 128) vcs[tid] = S16 * rcp_clamp(vw[half * 128 + tid]);
    }
    __syncthreads();

    const float* ep = encQ + b * 65536 + half * 32768 + (m << 2);
    F4 Ea = ld4(ep);
    F4 Eb = ld4(ep + 1024);
    ep += 2048;

    float acc[4] = {};

    #pragma unroll 4
    for (int o = 0; o < 16; ++o) {
        // always-prefetch next octet; final read spills into next region (harmless)
        const F4 Ena = ld4(ep);
        const F4 Enb = ld4(ep + 1024);
        ep += 2048;
        const int u0 = o << 3;
        const F4 ca = ld4(&vcs[u0]);
        const F4 cb = ld4(&vcs[u0 + 4]);
        #pragma unroll
        for (int c = 0; c < 4; ++c) {
            const F4 da = ld4(&dsD[t0 + c][u0]);
            const F4 db = ld4(&dsD[t0 + c][u0 + 4]);
            const float z0 = fmaf(Ea.v[0], da.v[0], ca.v[0]);
            const float z1 = fmaf(Ea.v[1], da.v[1], ca.v[1]);
            const float z2 = fmaf(Ea.v[2], da.v[2], ca.v[2]);
            const float z3 = fmaf(Ea.v[3], da.v[3], ca.v[3]);
            const float y0 = fmaf(Eb.v[0], db.v[0], cb.v[0]);
            const float y1 = fmaf(Eb.v[1], db.v[1], cb.v[1]);
            const float y2 = fmaf(Eb.v[2], db.v[2], cb.v[2]);
            const float y3 = fmaf(Eb.v[3], db.v[3], cb.v[3]);
            const float pz01 = z0 * z1, pz23 = z2 * z3;
            const float py01 = y0 * y1, py23 = y2 * y3;
            const float nz = fmaf(z0 + z1, pz23, (z2 + z3) * pz01);
            const float ny = fmaf(y0 + y1, py23, (y2 + y3) * py01);
            const float pz = pz01 * pz23, py = py01 * py23;
            const float num = fmaf(nz, py, ny * pz);
            acc[c] = fmaf(num, __builtin_amdgcn_rcpf(pz * py), acc[c]);
        }
        Ea = Ena; Eb = Enb;
    }

    #pragma unroll
    for (int c = 0; c < 4; ++c)
        part[((half << 4) + b) * 65536 + (n0 + t0 + c) * 256 + m] = acc[c] * LSC;
}

// ---------------- Kernel 3: partial-sum + softmax + context.
// Phase A (m = tid&255, half h owns 4 chains): l = part0+part1, softmax.
// Phase B (remap: dq = tid&63 -> d-quad, nc = tid>>6 -> chain): float4 ctx.
// Grid (32,16), 512 thr.
__global__ __launch_bounds__(512) void smctx_kernel(
    const float* __restrict__ enc,   // [B][M][D]
    const float* __restrict__ part,  // [2][B][N][M] partial logits
    float* __restrict__ out_attn,    // [B][N][M]
    float* __restrict__ out_ctx)     // [B][N][D]
{
    __shared__ float attn_s[8][256];
    __shared__ float redm[8][4], reds[8][4];

    const int tid = threadIdx.x;     // 0..511
    const int b   = blockIdx.y;
    const int n0  = blockIdx.x << 3;
    const int h   = tid >> 8;
    const int m   = tid & 255;
    const int t0  = h << 2;

    float l[4];
    #pragma unroll
    for (int c = 0; c < 4; ++c) {
        const int off = (b * 256 + n0 + t0 + c) * 256 + m;
        l[c] = part[off] + part[(16 << 16) + off];   // half0 + half1
    }

    // ---- softmax over m (4 waves per half)
    const int lane = tid & 63, wq = (tid >> 6) & 3;
    #pragma unroll
    for (int c = 0; c < 4; ++c) {
        float x = l[c];
        #pragma unroll
        for (int off = 32; off > 0; off >>= 1)
            x = fmaxf(x, __shfl_xor(x, off));
        if (lane == 0) redm[t0 + c][wq] = x;
    }
    __syncthreads();
    float p[4];
    #pragma unroll
    for (int c = 0; c < 4; ++c) {
        const float mx = fmaxf(fmaxf(redm[t0 + c][0], redm[t0 + c][1]),
                               fmaxf(redm[t0 + c][2], redm[t0 + c][3]));
        p[c] = __builtin_amdgcn_exp2f((l[c] - mx) * LOG2E);
    }
    #pragma unroll
    for (int c = 0; c < 4; ++c) {
        float x = p[c];
        #pragma unroll
        for (int off = 32; off > 0; off >>= 1)
            x += __shfl_xor(x, off);
        if (lane == 0) reds[t0 + c][wq] = x;
    }
    __syncthreads();
    #pragma unroll
    for (int c = 0; c < 4; ++c) {
        const float s = (reds[t0 + c][0] + reds[t0 + c][1])
                      + (reds[t0 + c][2] + reds[t0 + c][3]);
        const float w = p[c] * __builtin_amdgcn_rcpf(s);
        attn_s[t0 + c][m] = w;
        out_attn[(b * 256 + n0 + t0 + c) * 256 + m] = w;
    }
    __syncthreads();

    // ---- context, d-quad layout: thread (dq, nc) owns ctx[nc][4dq..4dq+3]
    const int dq = tid & 63, nc = tid >> 6;     // nc 0..7 wave-uniform
    const int d0 = dq << 2;
    const float* eb = enc + b * 65536 + d0;
    float cx[4] = {};
    #pragma unroll 4
    for (int mm = 0; mm < 256; mm += 4) {
        const F4 aq = ld4(&attn_s[nc][mm]);     // broadcast b128
        #pragma unroll
        for (int j = 0; j < 4; ++j) {
            const F4 ev = ld4(eb + (mm + j) * 256);
            cx[0] = fmaf(aq.v[j], ev.v[0], cx[0]);
            cx[1] = fmaf(aq.v[j], ev.v[1], cx[1]);
            cx[2] = fmaf(aq.v[j], ev.v[2], cx[2]);
            cx[3] = fmaf(aq.v[j], ev.v[3], cx[3]);
        }
    }
    float4 o; o.x = cx[0]; o.y = cx[1]; o.z = cx[2]; o.w = cx[3];
    *(float4*)&out_ctx[(b * 256 + n0 + nc) * 256 + d0] = o;
}

extern "C" void kernel_launch(void* const* d_in, const int* in_sizes, int n_in,
                              void* d_out, int out_size, void* d_ws, size_t ws_size,
                              hipStream_t stream) {
    const float* enc = (const float*)d_in[0];
    const float* dec = (const float*)d_in[1];
    const float* W1  = (const float*)d_in[2];
    const float* b1  = (const float*)d_in[3];
    const float* W2  = (const float*)d_in[4];
    const float* b2  = (const float*)d_in[5];
    const float* vw  = (const float*)d_in[6];
    // d_in[7] (v_b) cancels in softmax — unused.

    float* out_ctx  = (float*)d_out;
    float* out_attn = (float*)d_out + 16 * 256 * 256;

    float* encQ = (float*)d_ws;                 // 4 MB
    float* decE = encQ + 16 * 256 * 256;        // 4 MB
    float* part = decE + 16 * 256 * 256;        // 8 MB (2 halves)

    proj_kernel <<<dim3(16, 64),    256, 0, stream>>>(enc, dec, W1, b1, W2, b2, vw, encQ, decE);
    logit_kernel<<<dim3(32, 16, 2), 512, 0, stream>>>(encQ, decE, vw, part);
    smctx_kernel<<<dim3(32, 16),    512, 0, stream>>>(enc, part, out_attn, out_ctx);
}

// Round 9
// 169.425 us; speedup vs baseline: 1.1565x; 1.1565x over previous
//
#include <hip/hip_runtime.h>

// RetrosynthesisAttention, B=16, N=M=D=U=256, fp32 — split-phase build:
//   proj_kernel  : LDS-free GEMMs — X rows via wave-uniform s_load (scalar
//                  pipe), W via per-lane coalesced vector loads + exp2 epilogue
//   logit_kernel : logits, m-split x2, n-tile 8, 2 chains/thread, 8-way rcp
//   smctx_kernel : softmax + d-quad float4 context
//
// Math: tanh(x) = 1 - 2/(exp2(Kx)+1); constants cancel in softmax.
// z_u = rcpc(v_u)*2^-16 + E'_u*(D_u*rcpc(v_u)), E' = exp2(K*ep-16), D*rcpc(v)
// precomputed; sum 1/z over 8 u's with ONE v_rcp (tree combine).

constexpr float KSC   = 2.8853900817779268f;   // 2*log2(e)
constexpr float LOG2E = 1.4426950408889634f;
constexpr float S16   = 1.52587890625e-05f;    // 2^-16
constexpr float LSC   = -3.0517578125e-05f;    // -2^-15

struct F4 { float v[4]; };
__device__ __forceinline__ F4 ld4(const float* p) {
    float4 t = *(const float4*)p;
    F4 r; r.v[0] = t.x; r.v[1] = t.y; r.v[2] = t.z; r.v[3] = t.w; return r;
}
__device__ __forceinline__ float rcp_clamp(float v) {
    float r = __builtin_amdgcn_rcpf(v);
    return fminf(fmaxf(r, -1e4f), 1e4f);   // identical in all kernels
}

// ---------------- Kernel 1: LDS-free projection GEMMs + exp2 epilogue.
// Wave owns 4 UNIFORM rows (X via s_load_dwordx4, scalar pipe, no VMEM);
// lane owns u-quad (W float4: 64 lanes x 16B = contiguous 1KB, coalesced,
// L1-resident since all waves stream the same W rows). No LDS, no barriers.
// Block 256 thr = 4 waves = 16 rows. Grid 512 blocks (2/CU).
__global__ __launch_bounds__(256) void proj_kernel(
    const float* __restrict__ enc, const float* __restrict__ dec,
    const float* __restrict__ W1,  const float* __restrict__ b1,
    const float* __restrict__ W2,  const float* __restrict__ b2,
    const float* __restrict__ vw,
    float* __restrict__ encQ, float* __restrict__ decE)
{
    const int tid  = threadIdx.x;
    const int lane = tid & 63;
    const int w    = __builtin_amdgcn_readfirstlane(tid >> 6);  // 0..3, SGPR
    const int rblk = blockIdx.x;        // 0..511
    const bool is_enc = rblk < 256;
    const float* X    = is_enc ? enc : dec;
    const float* Wm   = is_enc ? W1  : W2;
    const float* bias = is_enc ? b1  : b2;
    const int rb = (is_enc ? rblk : rblk - 256) << 4;
    const int r0 = rb + (w << 2);       // wave's 4 rows (wave-uniform)
    const int u0 = lane << 2;           // lane's u-quad

    const float* x0 = X + r0 * 256;     // uniform pointers -> s_load
    const float* x1 = x0 + 256;
    const float* x2 = x1 + 256;
    const float* x3 = x2 + 256;
    const float* wp = Wm + u0;          // per-lane, coalesced across wave

    float acc[4][4] = {};
    #pragma unroll 4
    for (int kq = 0; kq < 64; ++kq) {
        const F4 xs0 = ld4(x0 + (kq << 2));   // scalar loads (uniform addr)
        const F4 xs1 = ld4(x1 + (kq << 2));
        const F4 xs2 = ld4(x2 + (kq << 2));
        const F4 xs3 = ld4(x3 + (kq << 2));
        #pragma unroll
        for (int j = 0; j < 4; ++j) {         // k = kq*4 + j
            const F4 wv = ld4(wp + ((kq << 2) + j) * 256);
            #pragma unroll
            for (int u = 0; u < 4; ++u) {
                acc[0][u] = fmaf(xs0.v[j], wv.v[u], acc[0][u]);
                acc[1][u] = fmaf(xs1.v[j], wv.v[u], acc[1][u]);
                acc[2][u] = fmaf(xs2.v[j], wv.v[u], acc[2][u]);
                acc[3][u] = fmaf(xs3.v[j], wv.v[u], acc[3][u]);
            }
        }
    }

    const F4 bb = ld4(&bias[u0]);
    if (is_enc) {
        #pragma unroll
        for (int i = 0; i < 4; ++i) {
            const int r = r0 + i, b = r >> 8, m = r & 255;
            float4 o;
            o.x = __builtin_amdgcn_exp2f(fmaf(KSC, acc[i][0] + bb.v[0], -16.f));
            o.y = __builtin_amdgcn_exp2f(fmaf(KSC, acc[i][1] + bb.v[1], -16.f));
            o.z = __builtin_amdgcn_exp2f(fmaf(KSC, acc[i][2] + bb.v[2], -16.f));
            o.w = __builtin_amdgcn_exp2f(fmaf(KSC, acc[i][3] + bb.v[3], -16.f));
            *(float4*)&encQ[b * 65536 + lane * 1024 + m * 4] = o;
        }
    } else {
        const F4 vv = ld4(&vw[u0]);
        float rv[4];
        #pragma unroll
        for (int j = 0; j < 4; ++j) rv[j] = rcp_clamp(vv.v[j]);
        #pragma unroll
        for (int i = 0; i < 4; ++i) {
            float4 o;
            o.x = __builtin_amdgcn_exp2f(KSC * (acc[i][0] + bb.v[0])) * rv[0];
            o.y = __builtin_amdgcn_exp2f(KSC * (acc[i][1] + bb.v[1])) * rv[1];
            o.z = __builtin_amdgcn_exp2f(KSC * (acc[i][2] + bb.v[2])) * rv[2];
            o.w = __builtin_amdgcn_exp2f(KSC * (acc[i][3] + bb.v[3])) * rv[3];
            *(float4*)&decE[(r0 + i) * 256 + u0] = o;
        }
    }
}

// ---------------- Kernel 2: logits. m-split x2 via blockIdx.z (no partials).
// 512 thr: group g = tid>>7 owns chains {2g, 2g+1}; ml = tid&127 -> m.
// Grid (32,16,2) = 1024 blocks -> 4 blk/CU, 32 waves/CU theoretical.
// Same-m groups read identical E lines -> L1 coalesced broadcast.
__global__ __launch_bounds__(512) void logit_kernel(
    const float* __restrict__ encQ,  // [b][u/4][m][4] = exp2(K*ep-16)
    const float* __restrict__ decE,  // [n_flat][u]    = exp2(K*dp)*rcpc(v)
    const float* __restrict__ vw,    // [U]
    float* __restrict__ logits)      // [B][N][M] (= out_attn region)
{
    __shared__ float dsD[8][256];
    __shared__ float vcs[256];

    const int tid = threadIdx.x;     // 0..511
    const int b   = blockIdx.y;
    const int n0  = blockIdx.x << 3;
    const int mh  = blockIdx.z;
    const int g   = tid >> 7;        // 0..3 -> chains {2g, 2g+1}
    const int ml  = tid & 127;
    const int m   = (mh << 7) + ml;
    const int t0  = g << 1;

    {   // stage decE rows n0..n0+7 and vcs = 2^-16 * rcpc(v)
        const float* dsrc = decE + (b * 256 + n0) * 256;
        #pragma unroll
        for (int i = 0; i < 4; ++i)
            ((float*)dsD)[tid + (i << 9)] = dsrc[tid + (i << 9)];
        if (tid < 256) vcs[tid] = S16 * rcp_clamp(vw[tid]);
    }
    __syncthreads();

    const float* ep = encQ + b * 65536 + (m << 2);
    F4 Ea = ld4(ep);
    F4 Eb = ld4(ep + 1024);
    ep += 2048;

    float acc[2] = {};

    #pragma unroll 4
    for (int o = 0; o < 32; ++o) {
        // always-prefetch next octet; final read spills into decE (harmless)
        const F4 Ena = ld4(ep);
        const F4 Enb = ld4(ep + 1024);
        ep += 2048;
        const int u0 = o << 3;
        const F4 ca = ld4(&vcs[u0]);
        const F4 cb = ld4(&vcs[u0 + 4]);
        #pragma unroll
        for (int c = 0; c < 2; ++c) {
            const F4 da = ld4(&dsD[t0 + c][u0]);
            const F4 db = ld4(&dsD[t0 + c][u0 + 4]);
            const float z0 = fmaf(Ea.v[0], da.v[0], ca.v[0]);
            const float z1 = fmaf(Ea.v[1], da.v[1], ca.v[1]);
            const float z2 = fmaf(Ea.v[2], da.v[2], ca.v[2]);
            const float z3 = fmaf(Ea.v[3], da.v[3], ca.v[3]);
            const float y0 = fmaf(Eb.v[0], db.v[0], cb.v[0]);
            const float y1 = fmaf(Eb.v[1], db.v[1], cb.v[1]);
            const float y2 = fmaf(Eb.v[2], db.v[2], cb.v[2]);
            const float y3 = fmaf(Eb.v[3], db.v[3], cb.v[3]);
            const float pz01 = z0 * z1, pz23 = z2 * z3;
            const float py01 = y0 * y1, py23 = y2 * y3;
            const float nz = fmaf(z0 + z1, pz23, (z2 + z3) * pz01);
            const float ny = fmaf(y0 + y1, py23, (y2 + y3) * py01);
            const float pz = pz01 * pz23, py = py01 * py23;
            const float num = fmaf(nz, py, ny * pz);
            acc[c] = fmaf(num, __builtin_amdgcn_rcpf(pz * py), acc[c]);
        }
        Ea = Ena; Eb = Enb;
    }

    logits[(b * 256 + n0 + t0 + 0) * 256 + m] = acc[0] * LSC;
    logits[(b * 256 + n0 + t0 + 1) * 256 + m] = acc[1] * LSC;
}

// ---------------- Kernel 3: softmax + context. 512 thr, n-tile 8.
// Phase A: half h owns 4 chains, m = tid&255 -> softmax over m.
// Phase B remap: nc = tid>>6 -> chain, dq = tid&63 -> d-quad; float4 enc
// loads (coalesced 1KB/wave), attn via b128 LDS broadcasts. Grid (32,16).
__global__ __launch_bounds__(512) void smctx_kernel(
    const float* __restrict__ enc,   // [B][M][D]
    float* __restrict__ out_attn,    // in: logits, out: weights
    float* __restrict__ out_ctx)     // [B][N][D]
{
    __shared__ float attn_s[8][256];
    __shared__ float redm[8][4], reds[8][4];

    const int tid = threadIdx.x;     // 0..511
    const int b   = blockIdx.y;
    const int n0  = blockIdx.x << 3;
    const int h   = tid >> 8;
    const int m   = tid & 255;
    const int t0  = h << 2;

    float l[4];
    #pragma unroll
    for (int c = 0; c < 4; ++c)
        l[c] = out_attn[(b * 256 + n0 + t0 + c) * 256 + m];

    // ---- softmax over m (4 waves per half)
    const int lane = tid & 63, wq = (tid >> 6) & 3;
    #pragma unroll
    for (int c = 0; c < 4; ++c) {
        float x = l[c];
        #pragma unroll
        for (int off = 32; off > 0; off >>= 1)
            x = fmaxf(x, __shfl_xor(x, off));
        if (lane == 0) redm[t0 + c][wq] = x;
    }
    __syncthreads();
    float p[4];
    #pragma unroll
    for (int c = 0; c < 4; ++c) {
        const float mx = fmaxf(fmaxf(redm[t0 + c][0], redm[t0 + c][1]),
                               fmaxf(redm[t0 + c][2], redm[t0 + c][3]));
        p[c] = __builtin_amdgcn_exp2f((l[c] - mx) * LOG2E);
    }
    #pragma unroll
    for (int c = 0; c < 4; ++c) {
        float x = p[c];
        #pragma unroll
        for (int off = 32; off > 0; off >>= 1)
            x += __shfl_xor(x, off);
        if (lane == 0) reds[t0 + c][wq] = x;
    }
    __syncthreads();
    #pragma unroll
    for (int c = 0; c < 4; ++c) {
        const float s = (reds[t0 + c][0] + reds[t0 + c][1])
                      + (reds[t0 + c][2] + reds[t0 + c][3]);
        const float w = p[c] * __builtin_amdgcn_rcpf(s);
        attn_s[t0 + c][m] = w;
        out_attn[(b * 256 + n0 + t0 + c) * 256 + m] = w;
    }
    __syncthreads();

    // ---- context, d-quad layout: thread (dq, nc) owns ctx[nc][4dq..4dq+3]
    const int dq = tid & 63, nc = tid >> 6;     // nc wave-uniform
    const int d0 = dq << 2;
    const float* eb = enc + b * 65536 + d0;
    float cx[4] = {};
    #pragma unroll 4
    for (int mm = 0; mm < 256; mm += 4) {
        const F4 aq = ld4(&attn_s[nc][mm]);     // b128 broadcast
        #pragma unroll
        for (int j = 0; j < 4; ++j) {
            const F4 ev = ld4(eb + (mm + j) * 256);
            cx[0] = fmaf(aq.v[j], ev.v[0], cx[0]);
            cx[1] = fmaf(aq.v[j], ev.v[1], cx[1]);
            cx[2] = fmaf(aq.v[j], ev.v[2], cx[2]);
            cx[3] = fmaf(aq.v[j], ev.v[3], cx[3]);
        }
    }
    float4 o; o.x = cx[0]; o.y = cx[1]; o.z = cx[2]; o.w = cx[3];
    *(float4*)&out_ctx[(b * 256 + n0 + nc) * 256 + d0] = o;
}

extern "C" void kernel_launch(void* const* d_in, const int* in_sizes, int n_in,
                              void* d_out, int out_size, void* d_ws, size_t ws_size,
                              hipStream_t stream) {
    const float* enc = (const float*)d_in[0];
    const float* dec = (const float*)d_in[1];
    const float* W1  = (const float*)d_in[2];
    const float* b1  = (const float*)d_in[3];
    const float* W2  = (const float*)d_in[4];
    const float* b2  = (const float*)d_in[5];
    const float* vw  = (const float*)d_in[6];
    // d_in[7] (v_b) cancels in softmax — unused.

    float* out_ctx  = (float*)d_out;
    float* out_attn = (float*)d_out + 16 * 256 * 256;

    float* encQ = (float*)d_ws;                 // 4 MB
    float* decE = encQ + 16 * 256 * 256;        // 4 MB

    proj_kernel <<<dim3(512),       256, 0, stream>>>(enc, dec, W1, b1, W2, b2, vw, encQ, decE);
    logit_kernel<<<dim3(32, 16, 2), 512, 0, stream>>>(encQ, decE, vw, out_attn);
    smctx_kernel<<<dim3(32, 16),    512, 0, stream>>>(enc, out_attn, out_ctx);
}

// Round 10
// 132.034 us; speedup vs baseline: 1.4841x; 1.2832x over previous
//
#include <hip/hip_runtime.h>

// RetrosynthesisAttention, B=16, N=M=D=U=256, fp32 — split-phase build:
//   proj_kernel  : MFMA bf16 hi/lo 3-pass GEMMs ([8192x256]@[256x256]) + exp2
//   logit_kernel : r7 structure VERBATIM (best measured: 41 us)
//   smctx_kernel : r7 structure VERBATIM (best measured: 17 us)
//
// Math: tanh(x) = 1 - 2/(exp2(Kx)+1); constants cancel in softmax.
// z_u = rcpc(v_u)*2^-16 + E'_u*(D_u*rcpc(v_u)), E' = exp2(K*ep-16), D*rcpc(v)
// precomputed; sum 1/z over 8 u's with ONE v_rcp (tree combine).
// Proj precision: A=Ah+Al, W=Wh+Wl (bf16 truncation); Ah*Wh+Ah*Wl+Al*Wh in
// fp32 acc -> dropped Al*Wl ~ 2^-17 relative. MFMA 16x16x32_bf16 layouts
// (m89-verified): A[r][k] r=lane&15,k=(lane>>4)*8+j; B[k][c] c=lane&15 (read
// from W-transposed LDS); D[r][c] c=lane&15, r=(lane>>4)*4+reg.

constexpr float KSC   = 2.8853900817779268f;   // 2*log2(e)
constexpr float LOG2E = 1.4426950408889634f;
constexpr float S16   = 1.52587890625e-05f;    // 2^-16
constexpr float LSC   = -3.0517578125e-05f;    // -2^-15

struct F4 { float v[4]; };
__device__ __forceinline__ F4 ld4(const float* p) {
    float4 t = *(const float4*)p;
    F4 r; r.v[0] = t.x; r.v[1] = t.y; r.v[2] = t.z; r.v[3] = t.w; return r;
}
__device__ __forceinline__ float rcp_clamp(float v) {
    float r = __builtin_amdgcn_rcpf(v);
    return fminf(fmaxf(r, -1e4f), 1e4f);   // identical in all kernels
}

typedef __attribute__((ext_vector_type(8))) short bf16x8;
typedef __attribute__((ext_vector_type(4))) float f32x4;

// ---------------- Kernel 1: MFMA projection GEMMs + exp2 epilogue.
// Block 256 thr = 4 waves (2x2 of 32x32 wave-tiles) = 64 rows x 64 u.
// K-step 32. A staged [row][k] bf16 hi/lo; W staged TRANSPOSED [u][k] hi/lo
// (so B-fragments are contiguous-k b128 reads). Pad 40 shorts (80B rows:
// 16B-aligned b128, 2-way banks = free). Grid (4 u-blk, 128 row-blk).
__global__ __launch_bounds__(256) void proj_kernel(
    const float* __restrict__ enc, const float* __restrict__ dec,
    const float* __restrict__ W1,  const float* __restrict__ b1,
    const float* __restrict__ W2,  const float* __restrict__ b2,
    const float* __restrict__ vw,
    float* __restrict__ encQ, float* __restrict__ decE)
{
    __shared__ __align__(16) short Ah[64][40], Al[64][40];   // [row][k]
    __shared__ __align__(16) short Wh[64][40], Wl[64][40];   // [u][k]

    const int tid  = threadIdx.x;
    const int lane = tid & 63;
    const int wv   = tid >> 6;          // 0..3
    const int wr   = wv >> 1, wc = wv & 1;
    const int u0   = blockIdx.x << 6;   // 0,64,128,192
    const int rblk = blockIdx.y;        // 0..127 over 8192 flat rows
    const bool is_enc = rblk < 64;
    const float* X    = is_enc ? enc : dec;
    const float* Wm   = is_enc ? W1  : W2;
    const float* bias = is_enc ? b1  : b2;
    const int rb = (is_enc ? rblk : rblk - 64) << 6;   // row base within tensor

    const int r16 = lane & 15;
    const int kg8 = (lane >> 4) << 3;   // 0,8,16,24

    f32x4 acc[2][2] = {};

    for (int kt = 0; kt < 256; kt += 32) {
        {   // stage A[64 rows][32 k] -> hi/lo bf16, b128 writes
            const int row = tid >> 2, koct = (tid & 3) << 3;
            const float* src = X + (rb + row) * 256 + kt + koct;
            bf16x8 vh, vl;
            #pragma unroll
            for (int j = 0; j < 8; ++j) {
                const float x = src[j];
                const unsigned bx = __float_as_uint(x);
                const float fh = __uint_as_float(bx & 0xFFFF0000u);
                vh[j] = (short)(bx >> 16);
                vl[j] = (short)(__float_as_uint(x - fh) >> 16);
            }
            *reinterpret_cast<bf16x8*>(&Ah[row][koct]) = vh;
            *reinterpret_cast<bf16x8*>(&Al[row][koct]) = vl;
        }
        {   // stage W[32 k][64 u] -> TRANSPOSED [u][k] hi/lo, b128 writes
            const int ul = tid & 63, koct = (tid >> 6) << 3;
            const float* src = Wm + (kt + koct) * 256 + u0 + ul;
            bf16x8 vh, vl;
            #pragma unroll
            for (int j = 0; j < 8; ++j) {
                const float x = src[j * 256];
                const unsigned bx = __float_as_uint(x);
                const float fh = __uint_as_float(bx & 0xFFFF0000u);
                vh[j] = (short)(bx >> 16);
                vl[j] = (short)(__float_as_uint(x - fh) >> 16);
            }
            *reinterpret_cast<bf16x8*>(&Wh[ul][koct]) = vh;
            *reinterpret_cast<bf16x8*>(&Wl[ul][koct]) = vl;
        }
        __syncthreads();

        bf16x8 fah[2], fal[2], fbh[2], fbl[2];
        #pragma unroll
        for (int i = 0; i < 2; ++i) {
            const int ar = (wr << 5) + (i << 4) + r16;
            fah[i] = *reinterpret_cast<const bf16x8*>(&Ah[ar][kg8]);
            fal[i] = *reinterpret_cast<const bf16x8*>(&Al[ar][kg8]);
        }
        #pragma unroll
        for (int j = 0; j < 2; ++j) {
            const int wu = (wc << 5) + (j << 4) + r16;
            fbh[j] = *reinterpret_cast<const bf16x8*>(&Wh[wu][kg8]);
            fbl[j] = *reinterpret_cast<const bf16x8*>(&Wl[wu][kg8]);
        }
        #pragma unroll
        for (int i = 0; i < 2; ++i)
            #pragma unroll
            for (int j = 0; j < 2; ++j) {
                acc[i][j] = __builtin_amdgcn_mfma_f32_16x16x32_bf16(
                    fah[i], fbh[j], acc[i][j], 0, 0, 0);
                acc[i][j] = __builtin_amdgcn_mfma_f32_16x16x32_bf16(
                    fah[i], fbl[j], acc[i][j], 0, 0, 0);
                acc[i][j] = __builtin_amdgcn_mfma_f32_16x16x32_bf16(
                    fal[i], fbh[j], acc[i][j], 0, 0, 0);
            }
        __syncthreads();
    }

    // ---- epilogue: D[r][c] c=lane&15, r=(lane>>4)*4+reg
    const int kg = lane >> 4;
    float bb[2];
    #pragma unroll
    for (int j = 0; j < 2; ++j)
        bb[j] = bias[u0 + (wc << 5) + (j << 4) + r16];

    if (is_enc) {
        #pragma unroll
        for (int i = 0; i < 2; ++i)
            #pragma unroll
            for (int j = 0; j < 2; ++j) {
                const int gu = u0 + (wc << 5) + (j << 4) + r16;
                #pragma unroll
                for (int r = 0; r < 4; ++r) {
                    const int grow = rb + (wr << 5) + (i << 4) + (kg << 2) + r;
                    const int b = grow >> 8, m = grow & 255;
                    const float val = __builtin_amdgcn_exp2f(
                        fmaf(KSC, acc[i][j][r] + bb[j], -16.f));
                    encQ[b * 65536 + (gu >> 2) * 1024 + (m << 2) + (gu & 3)] = val;
                }
            }
    } else {
        float rv[2];
        #pragma unroll
        for (int j = 0; j < 2; ++j)
            rv[j] = rcp_clamp(vw[u0 + (wc << 5) + (j << 4) + r16]);
        #pragma unroll
        for (int i = 0; i < 2; ++i)
            #pragma unroll
            for (int j = 0; j < 2; ++j) {
                const int gu = u0 + (wc << 5) + (j << 4) + r16;
                #pragma unroll
                for (int r = 0; r < 4; ++r) {
                    const int grow = rb + (wr << 5) + (i << 4) + (kg << 2) + r;
                    const float val = __builtin_amdgcn_exp2f(
                        KSC * (acc[i][j][r] + bb[j])) * rv[j];
                    decE[grow * 256 + gu] = val;
                }
            }
    }
}

// ---------------- Kernel 2: logits (r7 VERBATIM). 512 thr, n-tile 8, half h
// owns chains t0=4h..4h+3, m = tid&255. Grid (32,16).
__global__ __launch_bounds__(512) void logit_kernel(
    const float* __restrict__ encQ,  // [b][u/4][m][4] = exp2(K*ep-16)
    const float* __restrict__ decE,  // [n_flat][u]    = exp2(K*dp)*rcpc(v)
    const float* __restrict__ vw,    // [U]
    float* __restrict__ logits)      // [B][N][M] (= out_attn region)
{
    __shared__ float dsD[8][256];
    __shared__ float vcs[256];

    const int tid = threadIdx.x;     // 0..511
    const int b   = blockIdx.y;
    const int n0  = blockIdx.x << 3;
    const int h   = tid >> 8;
    const int m   = tid & 255;
    const int t0  = h << 2;

    {   // stage decE rows n0..n0+7 and vcs = 2^-16 * rcpc(v)
        const float* dsrc = decE + (b * 256 + n0) * 256;
        #pragma unroll
        for (int i = 0; i < 4; ++i)
            ((float*)dsD)[tid + (i << 9)] = dsrc[tid + (i << 9)];
        if (tid < 256) vcs[tid] = S16 * rcp_clamp(vw[tid]);
    }
    __syncthreads();

    const float* ep = encQ + b * 65536 + (m << 2);
    F4 Ea = ld4(ep);
    F4 Eb = ld4(ep + 1024);
    ep += 2048;

    float acc[4] = {};

    #pragma unroll 4
    for (int o = 0; o < 32; ++o) {
        const F4 Ena = ld4(ep);
        const F4 Enb = ld4(ep + 1024);
        ep += 2048;
        const int u0 = o << 3;
        const F4 ca = ld4(&vcs[u0]);
        const F4 cb = ld4(&vcs[u0 + 4]);
        #pragma unroll
        for (int c = 0; c < 4; ++c) {
            const F4 da = ld4(&dsD[t0 + c][u0]);
            const F4 db = ld4(&dsD[t0 + c][u0 + 4]);
            const float z0 = fmaf(Ea.v[0], da.v[0], ca.v[0]);
            const float z1 = fmaf(Ea.v[1], da.v[1], ca.v[1]);
            const float z2 = fmaf(Ea.v[2], da.v[2], ca.v[2]);
            const float z3 = fmaf(Ea.v[3], da.v[3], ca.v[3]);
            const float y0 = fmaf(Eb.v[0], db.v[0], cb.v[0]);
            const float y1 = fmaf(Eb.v[1], db.v[1], cb.v[1]);
            const float y2 = fmaf(Eb.v[2], db.v[2], cb.v[2]);
            const float y3 = fmaf(Eb.v[3], db.v[3], cb.v[3]);
            const float pz01 = z0 * z1, pz23 = z2 * z3;
            const float py01 = y0 * y1, py23 = y2 * y3;
            const float nz = fmaf(z0 + z1, pz23, (z2 + z3) * pz01);
            const float ny = fmaf(y0 + y1, py23, (y2 + y3) * py01);
            const float pz = pz01 * pz23, py = py01 * py23;
            const float num = fmaf(nz, py, ny * pz);
            acc[c] = fmaf(num, __builtin_amdgcn_rcpf(pz * py), acc[c]);
        }
        Ea = Ena; Eb = Enb;
    }

    #pragma unroll
    for (int c = 0; c < 4; ++c)
        logits[(b * 256 + n0 + t0 + c) * 256 + m] = acc[c] * LSC;
}

// ---------------- Kernel 3: softmax + context (r7 VERBATIM). 512 thr. Grid (32,16).
__global__ __launch_bounds__(512) void smctx_kernel(
    const float* __restrict__ enc,   // [B][M][D]
    float* __restrict__ out_attn,    // in: logits, out: weights
    float* __restrict__ out_ctx)     // [B][N][D]
{
    __shared__ float attn_s[8][256];
    __shared__ float redm[8][4], reds[8][4];

    const int tid = threadIdx.x;     // 0..511
    const int b   = blockIdx.y;
    const int n0  = blockIdx.x << 3;
    const int h   = tid >> 8;
    const int m   = tid & 255;
    const int t0  = h << 2;

    float l[4];
    #pragma unroll
    for (int c = 0; c < 4; ++c)
        l[c] = out_attn[(b * 256 + n0 + t0 + c) * 256 + m];

    const int lane = tid & 63, wq = (tid >> 6) & 3;
    #pragma unroll
    for (int c = 0; c < 4; ++c) {
        float x = l[c];
        #pragma unroll
        for (int off = 32; off > 0; off >>= 1)
            x = fmaxf(x, __shfl_xor(x, off));
        if (lane == 0) redm[t0 + c][wq] = x;
    }
    __syncthreads();
    float p[4];
    #pragma unroll
    for (int c = 0; c < 4; ++c) {
        const float mx = fmaxf(fmaxf(redm[t0 + c][0], redm[t0 + c][1]),
                               fmaxf(redm[t0 + c][2], redm[t0 + c][3]));
        p[c] = __builtin_amdgcn_exp2f((l[c] - mx) * LOG2E);
    }
    #pragma unroll
    for (int c = 0; c < 4; ++c) {
        float x = p[c];
        #pragma unroll
        for (int off = 32; off > 0; off >>= 1)
            x += __shfl_xor(x, off);
        if (lane == 0) reds[t0 + c][wq] = x;
    }
    __syncthreads();
    #pragma unroll
    for (int c = 0; c < 4; ++c) {
        const float s = (reds[t0 + c][0] + reds[t0 + c][1])
                      + (reds[t0 + c][2] + reds[t0 + c][3]);
        const float w = p[c] * __builtin_amdgcn_rcpf(s);
        attn_s[t0 + c][m] = w;
        out_attn[(b * 256 + n0 + t0 + c) * 256 + m] = w;
    }
    __syncthreads();

    const float* eb = enc + b * 65536 + m;
    float cx[4] = {};
    #pragma unroll 4
    for (int mm = 0; mm < 256; mm += 4) {
        const float g0 = eb[(mm + 0) << 8];
        const float g1 = eb[(mm + 1) << 8];
        const float g2 = eb[(mm + 2) << 8];
        const float g3 = eb[(mm + 3) << 8];
        #pragma unroll
        for (int c = 0; c < 4; ++c) {
            const F4 aq = ld4(&attn_s[t0 + c][mm]);
            cx[c] = fmaf(aq.v[0], g0, cx[c]);
            cx[c] = fmaf(aq.v[1], g1, cx[c]);
            cx[c] = fmaf(aq.v[2], g2, cx[c]);
            cx[c] = fmaf(aq.v[3], g3, cx[c]);
        }
    }
    #pragma unroll
    for (int c = 0; c < 4; ++c)
        out_ctx[(b * 256 + n0 + t0 + c) * 256 + m] = cx[c];
}

extern "C" void kernel_launch(void* const* d_in, const int* in_sizes, int n_in,
                              void* d_out, int out_size, void* d_ws, size_t ws_size,
                              hipStream_t stream) {
    const float* enc = (const float*)d_in[0];
    const float* dec = (const float*)d_in[1];
    const float* W1  = (const float*)d_in[2];
    const float* b1  = (const float*)d_in[3];
    const float* W2  = (const float*)d_in[4];
    const float* b2  = (const float*)d_in[5];
    const float* vw  = (const float*)d_in[6];
    // d_in[7] (v_b) cancels in softmax — unused.

    float* out_ctx  = (float*)d_out;
    float* out_attn = (float*)d_out + 16 * 256 * 256;

    float* encQ = (float*)d_ws;                 // 4 MB
    float* decE = encQ + 16 * 256 * 256;        // 4 MB

    proj_kernel <<<dim3(4, 128), 256, 0, stream>>>(enc, dec, W1, b1, W2, b2, vw, encQ, decE);
    logit_kernel<<<dim3(32, 16), 512, 0, stream>>>(encQ, decE, vw, out_attn);
    smctx_kernel<<<dim3(32, 16), 512, 0, stream>>>(enc, out_attn, out_ctx);
}